// Round 6
// baseline (365.847 us; speedup 1.0000x reference)
//
#include <hip/hip_runtime.h>
#include <stdint.h>

using u16 = unsigned short;
using short8 = __attribute__((ext_vector_type(8))) short;
using f32x4  = __attribute__((ext_vector_type(4))) float;
using u32x4  = __attribute__((ext_vector_type(4))) unsigned int;

__device__ __forceinline__ float bf2f(u16 u) {
  return __builtin_bit_cast(float, ((unsigned)u) << 16);
}
__device__ __forceinline__ u16 f2bf(float f) {
  unsigned u = __builtin_bit_cast(unsigned, f);
  u += 0x7FFFu + ((u >> 16) & 1u);   // RNE
  return (u16)(u >> 16);
}

// branchless insert of (d,s) into sorted top-3; strict < keeps earlier entries on ties
__device__ __forceinline__ void ins3(float& d0, float& d1, float& d2,
                                     int& i0, int& i1, int& i2, float d, int s) {
  bool c0 = d < d0, c1 = d < d1, c2 = d < d2;
  d2 = c1 ? d1 : (c2 ? d : d2);
  i2 = c1 ? i1 : (c2 ? s : i2);
  d1 = c0 ? d0 : (c1 ? d : d1);
  i1 = c0 ? i0 : (c1 ? s : i1);
  d0 = c0 ? d : d0;
  i0 = c0 ? s : i0;
}

// ---------------- 3-NN + inverse-distance weights (fp32 in) ----------------
// grid (N/32, B), block 256. 8 threads per query, each scans 128 candidates;
// partial top-3s merged via shfl_xor (lanes 8q..8q+7 are in the same wave).
// LDS: 8 staggered regions of 128 candidates; region stride 516 floats
// (2064 B, 16B-aligned, bank shift of 4 per region) -> conflict-free b128 reads.
// Scan metric is d' = |c|^2 - 2*p.c (per-query constant r1 folded out).
__global__ __launch_bounds__(256, 8) void nn3_kernel(
    const float* __restrict__ xyz1, const float* __restrict__ xyz2,
    int* __restrict__ idx_out, float* __restrict__ w_out) {
  __shared__ __align__(16) float cand[8 * 516];  // 16512 B
  const int b = blockIdx.y;
  const int t = threadIdx.x;
  const float* x2 = xyz2 + b * 3072;
  for (int i = t; i < 1024; i += 256) {
    float x = x2[i], y = x2[1024 + i], z = x2[2048 + i];
    f32x4 v = { -2.0f * x, -2.0f * y, -2.0f * z, x*x + y*y + z*z };
    *(f32x4*)&cand[(i >> 7) * 516 + (i & 127) * 4] = v;
  }
  __syncthreads();
  const int q = t >> 3, sub = t & 7;
  const int n = blockIdx.x * 32 + q;
  const float* x1 = xyz1 + b * 12288;
  const float px = x1[n], py = x1[4096 + n], pz = x1[8192 + n];
  float d0 = 1e30f, d1 = 1e30f, d2 = 1e30f;
  int i0 = 0, i1 = 0, i2 = 0;
  const int sbeg = sub << 7;
  const float* reg = &cand[sub * 516];
  #pragma unroll 4
  for (int ii = 0; ii < 128; ++ii) {
    f32x4 c = *(const f32x4*)(reg + ii * 4);
    float d = __builtin_fmaf(px, c[0],
              __builtin_fmaf(py, c[1],
              __builtin_fmaf(pz, c[2], c[3])));
    ins3(d0, d1, d2, i0, i1, i2, d, sbeg + ii);
  }
  // merge 8 partial lists, butterfly; a-list is always the lower-index range
  // on sub==0's tree -> ties keep earlier scan index.
  for (int st = 1; st <= 4; st <<= 1) {
    float e0 = __shfl_xor(d0, st), e1 = __shfl_xor(d1, st), e2 = __shfl_xor(d2, st);
    int   j0 = __shfl_xor(i0, st), j1 = __shfl_xor(i1, st), j2 = __shfl_xor(i2, st);
    ins3(d0, d1, d2, i0, i1, i2, e0, j0);
    ins3(d0, d1, d2, i0, i1, i2, e1, j1);
    ins3(d0, d1, d2, i0, i1, i2, e2, j2);
  }
  if (sub == 0) {
    const float r1 = px*px + py*py + pz*pz;  // add the folded-out constant back
    float w0 = 1.0f/(d0 + r1 + 1e-8f), w1 = 1.0f/(d1 + r1 + 1e-8f), w2 = 1.0f/(d2 + r1 + 1e-8f);
    float inv = 1.0f/(w0 + w1 + w2);
    const int pos = b * 4096 + n;
    idx_out[pos*3+0] = i0; idx_out[pos*3+1] = i1; idx_out[pos*3+2] = i2;
    w_out[pos*3+0] = w0*inv; w_out[pos*3+1] = w1*inv; w_out[pos*3+2] = w2*inv;
  }
}

// ---------------- [C=256][L] fp32 -> [L][C] bf16 transpose ----------------
// grid (L/64, 256/64, B), block 256.
__global__ __launch_bounds__(256) void transpose_cl(
    const float* __restrict__ in, u16* __restrict__ out, int L, int rstride) {
  __shared__ u16 tile[64][66];
  const int b = blockIdx.z;
  in  += (size_t)b * 256 * L;
  out += (size_t)b * L * rstride;
  const int n0 = blockIdx.x * 64, c0 = blockIdx.y * 64;
  const int t = threadIdx.x, ln = t & 63, grp = t >> 6;
  for (int p = 0; p < 16; ++p) {
    int cc = p*4 + grp;
    tile[cc][ln] = f2bf(in[(size_t)(c0 + cc) * L + n0 + ln]);
  }
  __syncthreads();
  for (int p = 0; p < 16; ++p) {
    int nn = p*4 + grp;
    out[(size_t)(n0 + nn) * rstride + c0 + ln] = tile[ln][nn];
  }
}

// ---------------- fp32 -> bf16 weight conversion ----------------
__global__ __launch_bounds__(256) void cvt_kernel(const float* __restrict__ in,
                                                  u16* __restrict__ out, int n) {
  int i = blockIdx.x * 256 + threadIdx.x;
  if (i < n) out[i] = f2bf(in[i]);
}

// ---------------- 3-NN feature interpolation into A1 cols 256..511 ----------------
// grid 1024, block 256: 4 lane-groups of 64, each group does one position with
// ushort4 (8B) gathers; 16 iterations -> 64 positions per block.
__global__ __launch_bounds__(256) void interp_kernel(
    const u16* __restrict__ p2t, const int* __restrict__ idx,
    const float* __restrict__ wgt, u16* __restrict__ A1) {
  const int t = threadIdx.x;
  const int ln = t & 63, grp = t >> 6;
  const int c0 = ln * 4;
  for (int i = 0; i < 16; ++i) {
    const int pos = blockIdx.x * 64 + i * 4 + grp;
    const int b = pos >> 12;
    const int j0 = idx[pos*3+0], j1 = idx[pos*3+1], j2 = idx[pos*3+2];
    const float w0 = wgt[pos*3+0], w1 = wgt[pos*3+1], w2 = wgt[pos*3+2];
    ushort4 v0 = *(const ushort4*)(p2t + ((size_t)(b*1024 + j0)) * 256 + c0);
    ushort4 v1 = *(const ushort4*)(p2t + ((size_t)(b*1024 + j1)) * 256 + c0);
    ushort4 v2 = *(const ushort4*)(p2t + ((size_t)(b*1024 + j2)) * 256 + c0);
    ushort4 o;
    o.x = f2bf(w0*bf2f(v0.x) + w1*bf2f(v1.x) + w2*bf2f(v2.x));
    o.y = f2bf(w0*bf2f(v0.y) + w1*bf2f(v1.y) + w2*bf2f(v2.y));
    o.z = f2bf(w0*bf2f(v0.z) + w1*bf2f(v1.z) + w2*bf2f(v2.z));
    o.w = f2bf(w0*bf2f(v0.w) + w1*bf2f(v1.w) + w2*bf2f(v2.w));
    *(ushort4*)(A1 + (size_t)pos*512 + 256 + c0) = o;
  }
}

// ---------------- bf16 GEMM + fused per-channel stats ----------------
// Y[m][n] = sum_k A[m][k]*Bw[n][k] + bias[n]; also atomically accumulates
// column sum / sumsq of the fp32 (pre-bf16) outputs into sums/sumsq.
// A: [M][K] bf16; Bw: [N][K] bf16; grid (M/128, N/128), block 256 (4 waves,
// 2x2 of 64x64 per wave).
// ROUND-1 STRUCTURE (measured best, 40.4 us): reg-staged global->LDS with TWO
// barriers per K-step; the COMPILER hoists the next step's global loads above
// the second barrier (manual pipelining variants all regressed: r3 gload_lds
// 80us, r4 gload_lds+dbuf 67us, r5 reg-dbuf 1-barrier 67us).
// LDS row stride 40 u16 = 80 B: read bank = (lc*20+quad*4)%32, 8 distinct
// groups over lc=0..7 -> 2 lanes/bank-group = free (m136); stride 48 was 4-way.
__global__ __launch_bounds__(256) void gemm_kernel(
    const u16* __restrict__ A, const u16* __restrict__ Bw,
    const float* __restrict__ bias, u16* __restrict__ Y, int K,
    float* __restrict__ sums, float* __restrict__ sumsq) {
  __shared__ __align__(16) u16 As[128*40];
  __shared__ __align__(16) u16 Bs[128*40];
  const int t = threadIdx.x;
  const int m0 = blockIdx.x * 128, n0 = blockIdx.y * 128;
  const int wave = t >> 6, l = t & 63;
  const int wm = wave & 1, wn = wave >> 1;
  const int lc = l & 15, quad = l >> 4;
  f32x4 acc[4][4] = {};
  const int rowA = t >> 2, kc = (t & 3) * 8;
  for (int k0 = 0; k0 < K; k0 += 32) {
    *(u32x4*)&As[rowA*40 + kc]      = *(const u32x4*)&A[(size_t)(m0 + rowA)*K + k0 + kc];
    *(u32x4*)&As[(rowA+64)*40 + kc] = *(const u32x4*)&A[(size_t)(m0 + rowA + 64)*K + k0 + kc];
    *(u32x4*)&Bs[rowA*40 + kc]      = *(const u32x4*)&Bw[(size_t)(n0 + rowA)*K + k0 + kc];
    *(u32x4*)&Bs[(rowA+64)*40 + kc] = *(const u32x4*)&Bw[(size_t)(n0 + rowA + 64)*K + k0 + kc];
    __syncthreads();
    short8 af[4], bfv[4];
    for (int tm = 0; tm < 4; ++tm)
      af[tm] = *(const short8*)&As[(wm*64 + tm*16 + lc)*40 + quad*8];   // A[m=lane&15][k=quad*8+j]
    for (int tn = 0; tn < 4; ++tn)
      bfv[tn] = *(const short8*)&Bs[(wn*64 + tn*16 + lc)*40 + quad*8];  // B[n=lane&15][k=quad*8+j]
    for (int tm = 0; tm < 4; ++tm)
      for (int tn = 0; tn < 4; ++tn)
        acc[tm][tn] = __builtin_amdgcn_mfma_f32_16x16x32_bf16(af[tm], bfv[tn], acc[tm][tn], 0, 0, 0);
    __syncthreads();
  }
  for (int tn = 0; tn < 4; ++tn) {
    const int col = n0 + wn*64 + tn*16 + lc;
    const float bb = bias[col];
    float s = 0.0f, q = 0.0f;
    for (int tm = 0; tm < 4; ++tm) {
      const int row = m0 + wm*64 + tm*16 + quad*4;
      for (int r = 0; r < 4; ++r) {
        float v = acc[tm][tn][r] + bb;           // C/D: col=lane&15, row=quad*4+reg
        Y[(size_t)(row + r)*256 + col] = f2bf(v);
        s += v; q += v*v;
      }
    }
    // per-col reduce across the 4 quads holding this col, then one atomic/lane16
    s += __shfl_xor(s, 16); s += __shfl_xor(s, 32);
    q += __shfl_xor(q, 16); q += __shfl_xor(q, 32);
    if (quad == 0) {
      atomicAdd(&sums[col],  s);
      atomicAdd(&sumsq[col], q);
    }
  }
}

__global__ void bnprep_kernel(const float* __restrict__ sums, const float* __restrict__ sumsq,
                              const float* __restrict__ g, const float* __restrict__ be,
                              float* __restrict__ scale, float* __restrict__ shift) {
  const int t = threadIdx.x;
  const float inv_n = 1.0f / 65536.0f;
  float mean = sums[t] * inv_n;
  float var = sumsq[t] * inv_n - mean*mean;  // biased var, matches jnp.var
  float a = g[t] * rsqrtf(var + 1e-5f);
  scale[t] = a;
  shift[t] = be[t] - mean * a;
}

// ---------------- BN+ReLU, pos-major bf16 output (GEMM2 input) ----------------
// grid 1024, block 256; each lane handles 4 contiguous channels (8B loads/stores).
__global__ __launch_bounds__(256) void bnrelu_kernel(
    const u16* __restrict__ Y, const float* __restrict__ scale,
    const float* __restrict__ shift, u16* __restrict__ X) {
  const int t = threadIdx.x;
  const int ln = t & 63, grp = t >> 6;
  const int c0 = ln * 4;
  const float a0 = scale[c0], a1 = scale[c0+1], a2 = scale[c0+2], a3 = scale[c0+3];
  const float s0 = shift[c0], s1 = shift[c0+1], s2 = shift[c0+2], s3 = shift[c0+3];
  size_t row0 = (size_t)blockIdx.x * 64;
  for (int it = 0; it < 16; ++it) {
    size_t off = (row0 + it*4 + grp) * 256 + c0;
    ushort4 v = *(const ushort4*)&Y[off];
    float f0 = bf2f(v.x)*a0 + s0, f1 = bf2f(v.y)*a1 + s1;
    float f2v = bf2f(v.z)*a2 + s2, f3 = bf2f(v.w)*a3 + s3;
    ushort4 o;
    o.x = f2bf(f0 > 0.0f ? f0 : 0.0f);
    o.y = f2bf(f1 > 0.0f ? f1 : 0.0f);
    o.z = f2bf(f2v > 0.0f ? f2v : 0.0f);
    o.w = f2bf(f3 > 0.0f ? f3 : 0.0f);
    *(ushort4*)&X[off] = o;
  }
}

// ---------------- BN+ReLU + transpose to [b][c][n] fp32 output ----------------
// grid (64, 1, 16), block 256 (thread = channel). ~Write-BW-bound (128 MB fp32).
__global__ __launch_bounds__(256) void bnrelu_tr_kernel(
    const u16* __restrict__ Y, const float* __restrict__ scale,
    const float* __restrict__ shift, float* __restrict__ out) {
  __shared__ u16 tile[256][66];
  const int t = threadIdx.x;
  const int b = blockIdx.z;
  const int n0 = blockIdx.x * 64;
  const float a = scale[t], s = shift[t];
  for (int nn = 0; nn < 64; ++nn) {
    size_t pos = (size_t)b*4096 + n0 + nn;
    float v = bf2f(Y[pos*256 + t]) * a + s;
    tile[t][nn] = f2bf(v > 0.0f ? v : 0.0f);
  }
  __syncthreads();
  const int ln = t & 63, grp = t >> 6;
  for (int p = 0; p < 64; ++p) {
    int oo = p*4 + grp;
    out[((size_t)b*256 + oo)*4096 + n0 + ln] = bf2f(tile[oo][ln]);
  }
}

extern "C" void kernel_launch(void* const* d_in, const int* in_sizes, int n_in,
                              void* d_out, int out_size, void* d_ws, size_t ws_size,
                              hipStream_t stream) {
  const float* xyz1    = (const float*)d_in[0];
  const float* xyz2    = (const float*)d_in[1];
  const float* points1 = (const float*)d_in[2];
  const float* points2 = (const float*)d_in[3];
  const float* w0      = (const float*)d_in[4];
  const float* b0      = (const float*)d_in[5];
  const float* g0      = (const float*)d_in[6];
  const float* be0     = (const float*)d_in[7];
  const float* w1      = (const float*)d_in[8];
  const float* b1      = (const float*)d_in[9];
  const float* g1      = (const float*)d_in[10];
  const float* be1     = (const float*)d_in[11];
  float* out = (float*)d_out;

  // ---- workspace layout (~107 MiB used) ----
  char* ws = (char*)d_ws;
  u16*   A1   = (u16*)ws;                          // [65536][512] bf16, 64 MiB (dead after gemm1)
  u16*   X0   = (u16*)ws;                          // [65536][256] bf16, 32 MiB (overlays dead A1)
  u16*   Y    = (u16*)(ws + (64ull  << 20));       // [65536][256] bf16, 32 MiB
  u16*   p2t  = (u16*)(ws + (96ull  << 20));       // [16*1024][256] bf16, 8 MiB
  int*   idxb = (int*)(ws + (104ull << 20));       // 768 KiB
  float* wgtb = (float*)(ws + (105ull << 20));     // 768 KiB
  u16*   w0b  = (u16*)(ws + (106ull << 20));       // [256][512] bf16, 256 KiB
  u16*   w1b  = (u16*)(ws + (106ull << 20) + (256u << 10)); // [256][256] bf16, 128 KiB
  float* stats= (float*)(ws + (106ull << 20) + (512u << 10)); // 2048 floats

  float* sums0 = stats, *sumsq0 = stats + 256, *scale0 = stats + 512, *shift0 = stats + 768;
  float* sums1 = stats + 1024, *sumsq1 = stats + 1280, *scale1 = stats + 1536, *shift1 = stats + 1792;

  hipMemsetAsync(stats, 0, 2048 * sizeof(float), stream);
  nn3_kernel<<<dim3(128, 16), 256, 0, stream>>>(xyz1, xyz2, idxb, wgtb);
  transpose_cl<<<dim3(16, 4, 16), 256, 0, stream>>>(points2, p2t, 1024, 256);
  transpose_cl<<<dim3(64, 4, 16), 256, 0, stream>>>(points1, A1, 4096, 512);
  cvt_kernel<<<512, 256, 0, stream>>>(w0, w0b, 131072);
  cvt_kernel<<<256, 256, 0, stream>>>(w1, w1b, 65536);
  interp_kernel<<<1024, 256, 0, stream>>>(p2t, idxb, wgtb, A1);
  gemm_kernel<<<dim3(512, 2), 256, 0, stream>>>(A1, w0b, b0, Y, 512, sums0, sumsq0);
  bnprep_kernel<<<1, 256, 0, stream>>>(sums0, sumsq0, g0, be0, scale0, shift0);
  bnrelu_kernel<<<1024, 256, 0, stream>>>(Y, scale0, shift0, X0);
  gemm_kernel<<<dim3(512, 2), 256, 0, stream>>>(X0, w1b, b1, Y, 256, sums1, sumsq1);
  bnprep_kernel<<<1, 256, 0, stream>>>(sums1, sumsq1, g1, be1, scale1, shift1);
  bnrelu_tr_kernel<<<dim3(64, 1, 16), 256, 0, stream>>>(Y, scale1, shift1, out);
}

// Round 7
// 310.436 us; speedup vs baseline: 1.1785x; 1.1785x over previous
//
#include <hip/hip_runtime.h>
#include <stdint.h>

using u16 = unsigned short;
using short8 = __attribute__((ext_vector_type(8))) short;
using f32x4  = __attribute__((ext_vector_type(4))) float;
using u32x4  = __attribute__((ext_vector_type(4))) unsigned int;

__device__ __forceinline__ float bf2f(u16 u) {
  return __builtin_bit_cast(float, ((unsigned)u) << 16);
}
__device__ __forceinline__ u16 f2bf(float f) {
  unsigned u = __builtin_bit_cast(unsigned, f);
  u += 0x7FFFu + ((u >> 16) & 1u);   // RNE
  return (u16)(u >> 16);
}

// branchless insert of (d,s) into sorted top-3; strict < keeps earlier entries on ties
__device__ __forceinline__ void ins3(float& d0, float& d1, float& d2,
                                     int& i0, int& i1, int& i2, float d, int s) {
  bool c0 = d < d0, c1 = d < d1, c2 = d < d2;
  d2 = c1 ? d1 : (c2 ? d : d2);
  i2 = c1 ? i1 : (c2 ? s : i2);
  d1 = c0 ? d0 : (c1 ? d : d1);
  i1 = c0 ? i0 : (c1 ? s : i1);
  d0 = c0 ? d : d0;
  i0 = c0 ? s : i0;
}

// ---------------- 3-NN + inverse-distance weights (fp32 in) ----------------
// grid (N/32, B), block 256. 8 threads per query, each scans 128 candidates;
// partial top-3s merged via shfl_xor (lanes 8q..8q+7 are in the same wave).
// LDS: 8 staggered regions of 128 candidates; region stride 516 floats
// (2064 B, 16B-aligned, bank shift of 4 per region) -> conflict-free b128 reads.
// Scan metric is d' = |c|^2 - 2*p.c (per-query constant r1 folded out).
__global__ __launch_bounds__(256, 8) void nn3_kernel(
    const float* __restrict__ xyz1, const float* __restrict__ xyz2,
    int* __restrict__ idx_out, float* __restrict__ w_out) {
  __shared__ __align__(16) float cand[8 * 516];  // 16512 B
  const int b = blockIdx.y;
  const int t = threadIdx.x;
  const float* x2 = xyz2 + b * 3072;
  for (int i = t; i < 1024; i += 256) {
    float x = x2[i], y = x2[1024 + i], z = x2[2048 + i];
    f32x4 v = { -2.0f * x, -2.0f * y, -2.0f * z, x*x + y*y + z*z };
    *(f32x4*)&cand[(i >> 7) * 516 + (i & 127) * 4] = v;
  }
  __syncthreads();
  const int q = t >> 3, sub = t & 7;
  const int n = blockIdx.x * 32 + q;
  const float* x1 = xyz1 + b * 12288;
  const float px = x1[n], py = x1[4096 + n], pz = x1[8192 + n];
  float d0 = 1e30f, d1 = 1e30f, d2 = 1e30f;
  int i0 = 0, i1 = 0, i2 = 0;
  const int sbeg = sub << 7;
  const float* reg = &cand[sub * 516];
  #pragma unroll 4
  for (int ii = 0; ii < 128; ++ii) {
    f32x4 c = *(const f32x4*)(reg + ii * 4);
    float d = __builtin_fmaf(px, c[0],
              __builtin_fmaf(py, c[1],
              __builtin_fmaf(pz, c[2], c[3])));
    ins3(d0, d1, d2, i0, i1, i2, d, sbeg + ii);
  }
  // merge 8 partial lists, butterfly; a-list is always the lower-index range
  // on sub==0's tree -> ties keep earlier scan index.
  for (int st = 1; st <= 4; st <<= 1) {
    float e0 = __shfl_xor(d0, st), e1 = __shfl_xor(d1, st), e2 = __shfl_xor(d2, st);
    int   j0 = __shfl_xor(i0, st), j1 = __shfl_xor(i1, st), j2 = __shfl_xor(i2, st);
    ins3(d0, d1, d2, i0, i1, i2, e0, j0);
    ins3(d0, d1, d2, i0, i1, i2, e1, j1);
    ins3(d0, d1, d2, i0, i1, i2, e2, j2);
  }
  if (sub == 0) {
    const float r1 = px*px + py*py + pz*pz;  // add the folded-out constant back
    float w0 = 1.0f/(d0 + r1 + 1e-8f), w1 = 1.0f/(d1 + r1 + 1e-8f), w2 = 1.0f/(d2 + r1 + 1e-8f);
    float inv = 1.0f/(w0 + w1 + w2);
    const int pos = b * 4096 + n;
    idx_out[pos*3+0] = i0; idx_out[pos*3+1] = i1; idx_out[pos*3+2] = i2;
    w_out[pos*3+0] = w0*inv; w_out[pos*3+1] = w1*inv; w_out[pos*3+2] = w2*inv;
  }
}

// ---------------- [C=256][L] fp32 -> [L][C] bf16 transpose ----------------
// grid (L/64, 256/64, B), block 256.
__global__ __launch_bounds__(256) void transpose_cl(
    const float* __restrict__ in, u16* __restrict__ out, int L, int rstride) {
  __shared__ u16 tile[64][66];
  const int b = blockIdx.z;
  in  += (size_t)b * 256 * L;
  out += (size_t)b * L * rstride;
  const int n0 = blockIdx.x * 64, c0 = blockIdx.y * 64;
  const int t = threadIdx.x, ln = t & 63, grp = t >> 6;
  for (int p = 0; p < 16; ++p) {
    int cc = p*4 + grp;
    tile[cc][ln] = f2bf(in[(size_t)(c0 + cc) * L + n0 + ln]);
  }
  __syncthreads();
  for (int p = 0; p < 16; ++p) {
    int nn = p*4 + grp;
    out[(size_t)(n0 + nn) * rstride + c0 + ln] = tile[ln][nn];
  }
}

// ---------------- fp32 -> bf16 weight conversion ----------------
__global__ __launch_bounds__(256) void cvt_kernel(const float* __restrict__ in,
                                                  u16* __restrict__ out, int n) {
  int i = blockIdx.x * 256 + threadIdx.x;
  if (i < n) out[i] = f2bf(in[i]);
}

// ---------------- 3-NN feature interpolation into A1 cols 256..511 ----------------
// grid 1024, block 256: 4 lane-groups of 64, each group does one position with
// ushort4 (8B) gathers; 16 iterations -> 64 positions per block.
__global__ __launch_bounds__(256) void interp_kernel(
    const u16* __restrict__ p2t, const int* __restrict__ idx,
    const float* __restrict__ wgt, u16* __restrict__ A1) {
  const int t = threadIdx.x;
  const int ln = t & 63, grp = t >> 6;
  const int c0 = ln * 4;
  for (int i = 0; i < 16; ++i) {
    const int pos = blockIdx.x * 64 + i * 4 + grp;
    const int b = pos >> 12;
    const int j0 = idx[pos*3+0], j1 = idx[pos*3+1], j2 = idx[pos*3+2];
    const float w0 = wgt[pos*3+0], w1 = wgt[pos*3+1], w2 = wgt[pos*3+2];
    ushort4 v0 = *(const ushort4*)(p2t + ((size_t)(b*1024 + j0)) * 256 + c0);
    ushort4 v1 = *(const ushort4*)(p2t + ((size_t)(b*1024 + j1)) * 256 + c0);
    ushort4 v2 = *(const ushort4*)(p2t + ((size_t)(b*1024 + j2)) * 256 + c0);
    ushort4 o;
    o.x = f2bf(w0*bf2f(v0.x) + w1*bf2f(v1.x) + w2*bf2f(v2.x));
    o.y = f2bf(w0*bf2f(v0.y) + w1*bf2f(v1.y) + w2*bf2f(v2.y));
    o.z = f2bf(w0*bf2f(v0.z) + w1*bf2f(v1.z) + w2*bf2f(v2.z));
    o.w = f2bf(w0*bf2f(v0.w) + w1*bf2f(v1.w) + w2*bf2f(v2.w));
    *(ushort4*)(A1 + (size_t)pos*512 + 256 + c0) = o;
  }
}

// ---------------- bf16 GEMM + fused per-channel stats (low-contention) ------
// Y[m][n] = sum_k A[m][k]*Bw[n][k] + bias[n]. Round-1 K-loop (measured best:
// reg-staged, TWO barriers/step, compiler-scheduled; all manual pipelines
// regressed r3-r5). Stride 48 u16 (measured: 2.1M conflicts vs 4.2M at 40).
// Stats: wave shfl-reduce -> LDS atomic (reuses dead As) -> ONE global atomic
// per col per block into 8-way banked sums[8][256] (bank = blockIdx.x & 7).
// r6 lesson: per-wave global atomics to 512 addrs = 1024 collisions/addr
// = ~27 us tail per gemm (r1 MfmaUtil 16*40/67 = 9.6 = r6's, pure dilution).
__global__ __launch_bounds__(256) void gemm_kernel(
    const u16* __restrict__ A, const u16* __restrict__ Bw,
    const float* __restrict__ bias, u16* __restrict__ Y, int K,
    float* __restrict__ sums, float* __restrict__ sumsq) {
  __shared__ __align__(16) u16 As[128*48];
  __shared__ __align__(16) u16 Bs[128*48];
  const int t = threadIdx.x;
  const int m0 = blockIdx.x * 128, n0 = blockIdx.y * 128;
  const int wave = t >> 6, l = t & 63;
  const int wm = wave & 1, wn = wave >> 1;
  const int lc = l & 15, quad = l >> 4;
  f32x4 acc[4][4] = {};
  const int rowA = t >> 2, kc = (t & 3) * 8;
  for (int k0 = 0; k0 < K; k0 += 32) {
    *(u32x4*)&As[rowA*48 + kc]      = *(const u32x4*)&A[(size_t)(m0 + rowA)*K + k0 + kc];
    *(u32x4*)&As[(rowA+64)*48 + kc] = *(const u32x4*)&A[(size_t)(m0 + rowA + 64)*K + k0 + kc];
    *(u32x4*)&Bs[rowA*48 + kc]      = *(const u32x4*)&Bw[(size_t)(n0 + rowA)*K + k0 + kc];
    *(u32x4*)&Bs[(rowA+64)*48 + kc] = *(const u32x4*)&Bw[(size_t)(n0 + rowA + 64)*K + k0 + kc];
    __syncthreads();
    short8 af[4], bfv[4];
    for (int tm = 0; tm < 4; ++tm)
      af[tm] = *(const short8*)&As[(wm*64 + tm*16 + lc)*48 + quad*8];   // A[m=lane&15][k=quad*8+j]
    for (int tn = 0; tn < 4; ++tn)
      bfv[tn] = *(const short8*)&Bs[(wn*64 + tn*16 + lc)*48 + quad*8];  // B[n=lane&15][k=quad*8+j]
    for (int tm = 0; tm < 4; ++tm)
      for (int tn = 0; tn < 4; ++tn)
        acc[tm][tn] = __builtin_amdgcn_mfma_f32_16x16x32_bf16(af[tm], bfv[tn], acc[tm][tn], 0, 0, 0);
    __syncthreads();
  }
  // As is dead now -> reuse 1 KiB as the block's stats scratch.
  float* sl = (float*)As;            // sl[0..127]=sum per block-col, sl[128..255]=sumsq
  if (t < 256) sl[t] = 0.0f;
  __syncthreads();
  for (int tn = 0; tn < 4; ++tn) {
    const int colL = wn*64 + tn*16 + lc;          // col within block [0,128)
    const float bb = bias[n0 + colL];
    float s = 0.0f, q = 0.0f;
    for (int tm = 0; tm < 4; ++tm) {
      const int row = m0 + wm*64 + tm*16 + quad*4;
      for (int r = 0; r < 4; ++r) {
        float v = acc[tm][tn][r] + bb;            // C/D: col=lane&15, row=quad*4+reg
        Y[(size_t)(row + r)*256 + n0 + colL] = f2bf(v);
        s += v; q += v*v;
      }
    }
    // reduce the 4 quads holding this col, then LDS-atomic (2 waves/addr)
    s += __shfl_xor(s, 16); s += __shfl_xor(s, 32);
    q += __shfl_xor(q, 16); q += __shfl_xor(q, 32);
    if (quad == 0) {
      atomicAdd(&sl[colL], s);
      atomicAdd(&sl[128 + colL], q);
    }
  }
  __syncthreads();
  if (t < 128) {                     // one global atomic per col per block, 8-banked
    const int bank = (blockIdx.x & 7) * 256;
    atomicAdd(&sums [bank + n0 + t], sl[t]);
    atomicAdd(&sumsq[bank + n0 + t], sl[128 + t]);
  }
}

// sums/sumsq are [8][256] banks; reduce banks here.
__global__ void bnprep_kernel(const float* __restrict__ sums, const float* __restrict__ sumsq,
                              const float* __restrict__ g, const float* __restrict__ be,
                              float* __restrict__ scale, float* __restrict__ shift) {
  const int t = threadIdx.x;
  float s = 0.0f, q = 0.0f;
  for (int k = 0; k < 8; ++k) { s += sums[k*256 + t]; q += sumsq[k*256 + t]; }
  const float inv_n = 1.0f / 65536.0f;
  float mean = s * inv_n;
  float var = q * inv_n - mean*mean;  // biased var, matches jnp.var
  float a = g[t] * rsqrtf(var + 1e-5f);
  scale[t] = a;
  shift[t] = be[t] - mean * a;
}

// ---------------- BN+ReLU, pos-major bf16 output (GEMM2 input) ----------------
// grid 1024, block 256; each lane handles 4 contiguous channels (8B loads/stores).
__global__ __launch_bounds__(256) void bnrelu_kernel(
    const u16* __restrict__ Y, const float* __restrict__ scale,
    const float* __restrict__ shift, u16* __restrict__ X) {
  const int t = threadIdx.x;
  const int ln = t & 63, grp = t >> 6;
  const int c0 = ln * 4;
  const float a0 = scale[c0], a1 = scale[c0+1], a2 = scale[c0+2], a3 = scale[c0+3];
  const float s0 = shift[c0], s1 = shift[c0+1], s2 = shift[c0+2], s3 = shift[c0+3];
  size_t row0 = (size_t)blockIdx.x * 64;
  for (int it = 0; it < 16; ++it) {
    size_t off = (row0 + it*4 + grp) * 256 + c0;
    ushort4 v = *(const ushort4*)&Y[off];
    float f0 = bf2f(v.x)*a0 + s0, f1 = bf2f(v.y)*a1 + s1;
    float f2v = bf2f(v.z)*a2 + s2, f3 = bf2f(v.w)*a3 + s3;
    ushort4 o;
    o.x = f2bf(f0 > 0.0f ? f0 : 0.0f);
    o.y = f2bf(f1 > 0.0f ? f1 : 0.0f);
    o.z = f2bf(f2v > 0.0f ? f2v : 0.0f);
    o.w = f2bf(f3 > 0.0f ? f3 : 0.0f);
    *(ushort4*)&X[off] = o;
  }
}

// ---------------- BN+ReLU + transpose to [b][c][n] fp32 output ----------------
// grid (64, 1, 16), block 256 (thread = channel). ~Write-BW-bound (128 MB fp32).
__global__ __launch_bounds__(256) void bnrelu_tr_kernel(
    const u16* __restrict__ Y, const float* __restrict__ scale,
    const float* __restrict__ shift, float* __restrict__ out) {
  __shared__ u16 tile[256][66];
  const int t = threadIdx.x;
  const int b = blockIdx.z;
  const int n0 = blockIdx.x * 64;
  const float a = scale[t], s = shift[t];
  for (int nn = 0; nn < 64; ++nn) {
    size_t pos = (size_t)b*4096 + n0 + nn;
    float v = bf2f(Y[pos*256 + t]) * a + s;
    tile[t][nn] = f2bf(v > 0.0f ? v : 0.0f);
  }
  __syncthreads();
  const int ln = t & 63, grp = t >> 6;
  for (int p = 0; p < 64; ++p) {
    int oo = p*4 + grp;
    out[((size_t)b*256 + oo)*4096 + n0 + ln] = bf2f(tile[oo][ln]);
  }
}

extern "C" void kernel_launch(void* const* d_in, const int* in_sizes, int n_in,
                              void* d_out, int out_size, void* d_ws, size_t ws_size,
                              hipStream_t stream) {
  const float* xyz1    = (const float*)d_in[0];
  const float* xyz2    = (const float*)d_in[1];
  const float* points1 = (const float*)d_in[2];
  const float* points2 = (const float*)d_in[3];
  const float* w0      = (const float*)d_in[4];
  const float* b0      = (const float*)d_in[5];
  const float* g0      = (const float*)d_in[6];
  const float* be0     = (const float*)d_in[7];
  const float* w1      = (const float*)d_in[8];
  const float* b1      = (const float*)d_in[9];
  const float* g1      = (const float*)d_in[10];
  const float* be1     = (const float*)d_in[11];
  float* out = (float*)d_out;

  // ---- workspace layout (~107 MiB used) ----
  char* ws = (char*)d_ws;
  u16*   A1   = (u16*)ws;                          // [65536][512] bf16, 64 MiB (dead after gemm1)
  u16*   X0   = (u16*)ws;                          // [65536][256] bf16, 32 MiB (overlays dead A1)
  u16*   Y    = (u16*)(ws + (64ull  << 20));       // [65536][256] bf16, 32 MiB
  u16*   p2t  = (u16*)(ws + (96ull  << 20));       // [16*1024][256] bf16, 8 MiB
  int*   idxb = (int*)(ws + (104ull << 20));       // 768 KiB
  float* wgtb = (float*)(ws + (105ull << 20));     // 768 KiB
  u16*   w0b  = (u16*)(ws + (106ull << 20));       // [256][512] bf16, 256 KiB
  u16*   w1b  = (u16*)(ws + (106ull << 20) + (256u << 10)); // [256][256] bf16, 128 KiB
  float* stats= (float*)(ws + (106ull << 20) + (512u << 10)); // 9216 floats

  // banked accumulators [8][256] each, then scale/shift
  float* sums0  = stats;          // 2048
  float* sumsq0 = stats + 2048;   // 2048
  float* sums1  = stats + 4096;   // 2048
  float* sumsq1 = stats + 6144;   // 2048
  float* scale0 = stats + 8192, *shift0 = stats + 8448;
  float* scale1 = stats + 8704, *shift1 = stats + 8960;

  hipMemsetAsync(stats, 0, 8192 * sizeof(float), stream);
  nn3_kernel<<<dim3(128, 16), 256, 0, stream>>>(xyz1, xyz2, idxb, wgtb);
  transpose_cl<<<dim3(16, 4, 16), 256, 0, stream>>>(points2, p2t, 1024, 256);
  transpose_cl<<<dim3(64, 4, 16), 256, 0, stream>>>(points1, A1, 4096, 512);
  cvt_kernel<<<512, 256, 0, stream>>>(w0, w0b, 131072);
  cvt_kernel<<<256, 256, 0, stream>>>(w1, w1b, 65536);
  interp_kernel<<<1024, 256, 0, stream>>>(p2t, idxb, wgtb, A1);
  gemm_kernel<<<dim3(512, 2), 256, 0, stream>>>(A1, w0b, b0, Y, 512, sums0, sumsq0);
  bnprep_kernel<<<1, 256, 0, stream>>>(sums0, sumsq0, g0, be0, scale0, shift0);
  bnrelu_kernel<<<1024, 256, 0, stream>>>(Y, scale0, shift0, X0);
  gemm_kernel<<<dim3(512, 2), 256, 0, stream>>>(X0, w1b, b1, Y, 256, sums1, sumsq1);
  bnprep_kernel<<<1, 256, 0, stream>>>(sums1, sumsq1, g1, be1, scale1, shift1);
  bnrelu_tr_kernel<<<dim3(64, 1, 16), 256, 0, stream>>>(Y, scale1, shift1, out);
}

// Round 8
// 295.655 us; speedup vs baseline: 1.2374x; 1.0500x over previous
//
#include <hip/hip_runtime.h>
#include <stdint.h>

using u16 = unsigned short;
using short8 = __attribute__((ext_vector_type(8))) short;
using f32x4  = __attribute__((ext_vector_type(4))) float;
using u32x4  = __attribute__((ext_vector_type(4))) unsigned int;

__device__ __forceinline__ float bf2f(u16 u) {
  return __builtin_bit_cast(float, ((unsigned)u) << 16);
}
__device__ __forceinline__ u16 f2bf(float f) {
  unsigned u = __builtin_bit_cast(unsigned, f);
  u += 0x7FFFu + ((u >> 16) & 1u);   // RNE
  return (u16)(u >> 16);
}
// BN+ReLU on a packed pair of bf16 (used by the fused gemm2 staging path)
__device__ __forceinline__ unsigned bn2(unsigned w, float a0, float s0, float a1, float s1) {
  float f0 = bf2f((u16)(w & 0xFFFFu)) * a0 + s0;
  float f1 = bf2f((u16)(w >> 16))     * a1 + s1;
  f0 = f0 > 0.0f ? f0 : 0.0f;
  f1 = f1 > 0.0f ? f1 : 0.0f;
  return (unsigned)f2bf(f0) | ((unsigned)f2bf(f1) << 16);
}

// branchless insert of (d,s) into sorted top-3; strict < keeps earlier entries on ties
__device__ __forceinline__ void ins3(float& d0, float& d1, float& d2,
                                     int& i0, int& i1, int& i2, float d, int s) {
  bool c0 = d < d0, c1 = d < d1, c2 = d < d2;
  d2 = c1 ? d1 : (c2 ? d : d2);
  i2 = c1 ? i1 : (c2 ? s : i2);
  d1 = c0 ? d0 : (c1 ? d : d1);
  i1 = c0 ? i0 : (c1 ? s : i1);
  d0 = c0 ? d : d0;
  i0 = c0 ? s : i0;
}

// ---------------- 3-NN + inverse-distance weights (fp32 in) ----------------
// grid (N/32, B), block 256. 8 threads per query, each scans 128 candidates;
// partial top-3s merged via shfl_xor (lanes 8q..8q+7 are in the same wave).
// LDS: 8 staggered regions of 128 candidates; region stride 516 floats
// (2064 B, 16B-aligned, bank shift of 4 per region) -> conflict-free b128 reads.
// Scan metric is d' = |c|^2 - 2*p.c (per-query constant r1 folded out).
__global__ __launch_bounds__(256, 8) void nn3_kernel(
    const float* __restrict__ xyz1, const float* __restrict__ xyz2,
    int* __restrict__ idx_out, float* __restrict__ w_out) {
  __shared__ __align__(16) float cand[8 * 516];  // 16512 B
  const int b = blockIdx.y;
  const int t = threadIdx.x;
  const float* x2 = xyz2 + b * 3072;
  for (int i = t; i < 1024; i += 256) {
    float x = x2[i], y = x2[1024 + i], z = x2[2048 + i];
    f32x4 v = { -2.0f * x, -2.0f * y, -2.0f * z, x*x + y*y + z*z };
    *(f32x4*)&cand[(i >> 7) * 516 + (i & 127) * 4] = v;
  }
  __syncthreads();
  const int q = t >> 3, sub = t & 7;
  const int n = blockIdx.x * 32 + q;
  const float* x1 = xyz1 + b * 12288;
  const float px = x1[n], py = x1[4096 + n], pz = x1[8192 + n];
  float d0 = 1e30f, d1 = 1e30f, d2 = 1e30f;
  int i0 = 0, i1 = 0, i2 = 0;
  const int sbeg = sub << 7;
  const float* reg = &cand[sub * 516];
  #pragma unroll 4
  for (int ii = 0; ii < 128; ++ii) {
    f32x4 c = *(const f32x4*)(reg + ii * 4);
    float d = __builtin_fmaf(px, c[0],
              __builtin_fmaf(py, c[1],
              __builtin_fmaf(pz, c[2], c[3])));
    ins3(d0, d1, d2, i0, i1, i2, d, sbeg + ii);
  }
  // merge 8 partial lists, butterfly; a-list is always the lower-index range
  // on sub==0's tree -> ties keep earlier scan index.
  for (int st = 1; st <= 4; st <<= 1) {
    float e0 = __shfl_xor(d0, st), e1 = __shfl_xor(d1, st), e2 = __shfl_xor(d2, st);
    int   j0 = __shfl_xor(i0, st), j1 = __shfl_xor(i1, st), j2 = __shfl_xor(i2, st);
    ins3(d0, d1, d2, i0, i1, i2, e0, j0);
    ins3(d0, d1, d2, i0, i1, i2, e1, j1);
    ins3(d0, d1, d2, i0, i1, i2, e2, j2);
  }
  if (sub == 0) {
    const float r1 = px*px + py*py + pz*pz;  // add the folded-out constant back
    float w0 = 1.0f/(d0 + r1 + 1e-8f), w1 = 1.0f/(d1 + r1 + 1e-8f), w2 = 1.0f/(d2 + r1 + 1e-8f);
    float inv = 1.0f/(w0 + w1 + w2);
    const int pos = b * 4096 + n;
    idx_out[pos*3+0] = i0; idx_out[pos*3+1] = i1; idx_out[pos*3+2] = i2;
    w_out[pos*3+0] = w0*inv; w_out[pos*3+1] = w1*inv; w_out[pos*3+2] = w2*inv;
  }
}

// ---------------- [C=256][L] fp32 -> [L][C] bf16 transpose ----------------
// grid (L/64, 256/64, B), block 256.
__global__ __launch_bounds__(256) void transpose_cl(
    const float* __restrict__ in, u16* __restrict__ out, int L, int rstride) {
  __shared__ u16 tile[64][66];
  const int b = blockIdx.z;
  in  += (size_t)b * 256 * L;
  out += (size_t)b * L * rstride;
  const int n0 = blockIdx.x * 64, c0 = blockIdx.y * 64;
  const int t = threadIdx.x, ln = t & 63, grp = t >> 6;
  for (int p = 0; p < 16; ++p) {
    int cc = p*4 + grp;
    tile[cc][ln] = f2bf(in[(size_t)(c0 + cc) * L + n0 + ln]);
  }
  __syncthreads();
  for (int p = 0; p < 16; ++p) {
    int nn = p*4 + grp;
    out[(size_t)(n0 + nn) * rstride + c0 + ln] = tile[ln][nn];
  }
}

// ---------------- fp32 -> bf16 weight conversion ----------------
__global__ __launch_bounds__(256) void cvt_kernel(const float* __restrict__ in,
                                                  u16* __restrict__ out, int n) {
  int i = blockIdx.x * 256 + threadIdx.x;
  if (i < n) out[i] = f2bf(in[i]);
}

// ---------------- 3-NN feature interpolation into A1 cols 256..511 ----------------
// grid 1024, block 256: 4 lane-groups of 64, each group does one position with
// ushort4 (8B) gathers; 16 iterations -> 64 positions per block.
__global__ __launch_bounds__(256) void interp_kernel(
    const u16* __restrict__ p2t, const int* __restrict__ idx,
    const float* __restrict__ wgt, u16* __restrict__ A1) {
  const int t = threadIdx.x;
  const int ln = t & 63, grp = t >> 6;
  const int c0 = ln * 4;
  for (int i = 0; i < 16; ++i) {
    const int pos = blockIdx.x * 64 + i * 4 + grp;
    const int b = pos >> 12;
    const int j0 = idx[pos*3+0], j1 = idx[pos*3+1], j2 = idx[pos*3+2];
    const float w0 = wgt[pos*3+0], w1 = wgt[pos*3+1], w2 = wgt[pos*3+2];
    ushort4 v0 = *(const ushort4*)(p2t + ((size_t)(b*1024 + j0)) * 256 + c0);
    ushort4 v1 = *(const ushort4*)(p2t + ((size_t)(b*1024 + j1)) * 256 + c0);
    ushort4 v2 = *(const ushort4*)(p2t + ((size_t)(b*1024 + j2)) * 256 + c0);
    ushort4 o;
    o.x = f2bf(w0*bf2f(v0.x) + w1*bf2f(v1.x) + w2*bf2f(v2.x));
    o.y = f2bf(w0*bf2f(v0.y) + w1*bf2f(v1.y) + w2*bf2f(v2.y));
    o.z = f2bf(w0*bf2f(v0.z) + w1*bf2f(v1.z) + w2*bf2f(v2.z));
    o.w = f2bf(w0*bf2f(v0.w) + w1*bf2f(v1.w) + w2*bf2f(v2.w));
    *(ushort4*)(A1 + (size_t)pos*512 + 256 + c0) = o;
  }
}

// ---------------- bf16 GEMM + fused per-channel stats (+optional fused BN) ----
// Y[m][n] = sum_k Ain[m][k]*Bw[n][k] + bias[n], where Ain = A (FUSE=0) or
// Ain = relu(A*bn_scale[k]+bn_shift[k]) applied during staging (FUSE=1, bit-
// identical to the old standalone bnrelu kernel's bf16 output).
// grid (M/128, N/128), block 256 (4 waves, 2x2 of 64x64 per wave).
// K-loop: round-1 compiler-scheduled structure (reg-staged, 2 barriers/step;
// manual pipelines all regressed r3-r5), but BK=64: half the barriers, 2x the
// compute per vmcnt drain, 2x hoisting distance for next-step loads.
// LDS row stride 72 u16 = 144 B: b128 read window = (lc+quad)%8 and write
// window = (r+(l&7))%8 -> uniform 8 lanes/16B window = structural floor.
// Stats: wave shfl-reduce -> LDS atomic (dead As reuse) -> one global atomic
// per col per block into 8-way banked sums[8][256] (r6/r7 contention lesson).
template <int FUSE>
__global__ __launch_bounds__(256) void gemm_kernel(
    const u16* __restrict__ A, const u16* __restrict__ Bw,
    const float* __restrict__ bias, u16* __restrict__ Y, int K,
    float* __restrict__ sums, float* __restrict__ sumsq,
    const float* __restrict__ bn_scale, const float* __restrict__ bn_shift) {
  __shared__ __align__(16) u16 As[128*72];
  __shared__ __align__(16) u16 Bs[128*72];
  const int t = threadIdx.x;
  const int m0 = blockIdx.x * 128, n0 = blockIdx.y * 128;
  const int wave = t >> 6, l = t & 63;
  const int wm = wave & 1, wn = wave >> 1;
  const int lc = l & 15, quad = l >> 4;
  f32x4 acc[4][4] = {};
  const int r = t >> 3, kc = (t & 7) * 8;   // staging: 8 threads/row, 16B each
  for (int k0 = 0; k0 < K; k0 += 64) {
    f32x4 sc_lo, sc_hi, sh_lo, sh_hi;
    if (FUSE) {
      sc_lo = *(const f32x4*)&bn_scale[k0 + kc];
      sc_hi = *(const f32x4*)&bn_scale[k0 + kc + 4];
      sh_lo = *(const f32x4*)&bn_shift[k0 + kc];
      sh_hi = *(const f32x4*)&bn_shift[k0 + kc + 4];
    }
    #pragma unroll
    for (int p = 0; p < 4; ++p) {
      const int row = p*32 + r;
      u32x4 va = *(const u32x4*)&A [(size_t)(m0 + row)*K + k0 + kc];
      u32x4 vb = *(const u32x4*)&Bw[(size_t)(n0 + row)*K + k0 + kc];
      if (FUSE) {
        va[0] = bn2(va[0], sc_lo[0], sh_lo[0], sc_lo[1], sh_lo[1]);
        va[1] = bn2(va[1], sc_lo[2], sh_lo[2], sc_lo[3], sh_lo[3]);
        va[2] = bn2(va[2], sc_hi[0], sh_hi[0], sc_hi[1], sh_hi[1]);
        va[3] = bn2(va[3], sc_hi[2], sh_hi[2], sc_hi[3], sh_hi[3]);
      }
      *(u32x4*)&As[row*72 + kc] = va;
      *(u32x4*)&Bs[row*72 + kc] = vb;
    }
    __syncthreads();
    #pragma unroll
    for (int h = 0; h < 2; ++h) {
      short8 af[4], bfv[4];
      for (int tm = 0; tm < 4; ++tm)
        af[tm] = *(const short8*)&As[(wm*64 + tm*16 + lc)*72 + h*32 + quad*8];
      for (int tn = 0; tn < 4; ++tn)
        bfv[tn] = *(const short8*)&Bs[(wn*64 + tn*16 + lc)*72 + h*32 + quad*8];
      for (int tm = 0; tm < 4; ++tm)
        for (int tn = 0; tn < 4; ++tn)
          acc[tm][tn] = __builtin_amdgcn_mfma_f32_16x16x32_bf16(af[tm], bfv[tn], acc[tm][tn], 0, 0, 0);
    }
    __syncthreads();
  }
  // As is dead now -> reuse 1 KiB as the block's stats scratch.
  float* sl = (float*)As;            // sl[0..127]=sum per block-col, sl[128..255]=sumsq
  if (t < 256) sl[t] = 0.0f;
  __syncthreads();
  for (int tn = 0; tn < 4; ++tn) {
    const int colL = wn*64 + tn*16 + lc;          // col within block [0,128)
    const float bb = bias[n0 + colL];
    float s = 0.0f, q = 0.0f;
    for (int tm = 0; tm < 4; ++tm) {
      const int row = m0 + wm*64 + tm*16 + quad*4;
      for (int rr = 0; rr < 4; ++rr) {
        float v = acc[tm][tn][rr] + bb;           // C/D: col=lane&15, row=quad*4+reg
        Y[(size_t)(row + rr)*256 + n0 + colL] = f2bf(v);
        s += v; q += v*v;
      }
    }
    // reduce the 4 quads holding this col, then LDS-atomic (2 waves/addr)
    s += __shfl_xor(s, 16); s += __shfl_xor(s, 32);
    q += __shfl_xor(q, 16); q += __shfl_xor(q, 32);
    if (quad == 0) {
      atomicAdd(&sl[colL], s);
      atomicAdd(&sl[128 + colL], q);
    }
  }
  __syncthreads();
  if (t < 128) {                     // one global atomic per col per block, 8-banked
    const int bank = (blockIdx.x & 7) * 256;
    atomicAdd(&sums [bank + n0 + t], sl[t]);
    atomicAdd(&sumsq[bank + n0 + t], sl[128 + t]);
  }
}

// sums/sumsq are [8][256] banks; reduce banks here.
__global__ void bnprep_kernel(const float* __restrict__ sums, const float* __restrict__ sumsq,
                              const float* __restrict__ g, const float* __restrict__ be,
                              float* __restrict__ scale, float* __restrict__ shift) {
  const int t = threadIdx.x;
  float s = 0.0f, q = 0.0f;
  for (int k = 0; k < 8; ++k) { s += sums[k*256 + t]; q += sumsq[k*256 + t]; }
  const float inv_n = 1.0f / 65536.0f;
  float mean = s * inv_n;
  float var = q * inv_n - mean*mean;  // biased var, matches jnp.var
  float a = g[t] * rsqrtf(var + 1e-5f);
  scale[t] = a;
  shift[t] = be[t] - mean * a;
}

// ---------------- BN+ReLU + transpose to [b][c][n] fp32 output ----------------
// grid (64, 1, 16), block 256 (thread = channel). ~Write-BW-bound (~100 MB).
__global__ __launch_bounds__(256) void bnrelu_tr_kernel(
    const u16* __restrict__ Y, const float* __restrict__ scale,
    const float* __restrict__ shift, float* __restrict__ out) {
  __shared__ u16 tile[256][66];
  const int t = threadIdx.x;
  const int b = blockIdx.z;
  const int n0 = blockIdx.x * 64;
  const float a = scale[t], s = shift[t];
  for (int nn = 0; nn < 64; ++nn) {
    size_t pos = (size_t)b*4096 + n0 + nn;
    float v = bf2f(Y[pos*256 + t]) * a + s;
    tile[t][nn] = f2bf(v > 0.0f ? v : 0.0f);
  }
  __syncthreads();
  const int ln = t & 63, grp = t >> 6;
  for (int p = 0; p < 64; ++p) {
    int oo = p*4 + grp;
    out[((size_t)b*256 + oo)*4096 + n0 + ln] = bf2f(tile[oo][ln]);
  }
}

extern "C" void kernel_launch(void* const* d_in, const int* in_sizes, int n_in,
                              void* d_out, int out_size, void* d_ws, size_t ws_size,
                              hipStream_t stream) {
  const float* xyz1    = (const float*)d_in[0];
  const float* xyz2    = (const float*)d_in[1];
  const float* points1 = (const float*)d_in[2];
  const float* points2 = (const float*)d_in[3];
  const float* w0      = (const float*)d_in[4];
  const float* b0      = (const float*)d_in[5];
  const float* g0      = (const float*)d_in[6];
  const float* be0     = (const float*)d_in[7];
  const float* w1      = (const float*)d_in[8];
  const float* b1      = (const float*)d_in[9];
  const float* g1      = (const float*)d_in[10];
  const float* be1     = (const float*)d_in[11];
  float* out = (float*)d_out;

  // ---- workspace layout (~107 MiB used) ----
  char* ws = (char*)d_ws;
  u16*   A1   = (u16*)ws;                          // [65536][512] bf16, 64 MiB (dead after gemm1)
  u16*   Y2   = (u16*)ws;                          // [65536][256] bf16, 32 MiB (overlays dead A1)
  u16*   Y    = (u16*)(ws + (64ull  << 20));       // [65536][256] bf16, 32 MiB
  u16*   p2t  = (u16*)(ws + (96ull  << 20));       // [16*1024][256] bf16, 8 MiB
  int*   idxb = (int*)(ws + (104ull << 20));       // 768 KiB
  float* wgtb = (float*)(ws + (105ull << 20));     // 768 KiB
  u16*   w0b  = (u16*)(ws + (106ull << 20));       // [256][512] bf16, 256 KiB
  u16*   w1b  = (u16*)(ws + (106ull << 20) + (256u << 10)); // [256][256] bf16, 128 KiB
  float* stats= (float*)(ws + (106ull << 20) + (512u << 10)); // 9216 floats

  // banked accumulators [8][256] each, then scale/shift
  float* sums0  = stats;          // 2048
  float* sumsq0 = stats + 2048;   // 2048
  float* sums1  = stats + 4096;   // 2048
  float* sumsq1 = stats + 6144;   // 2048
  float* scale0 = stats + 8192, *shift0 = stats + 8448;
  float* scale1 = stats + 8704, *shift1 = stats + 8960;

  hipMemsetAsync(stats, 0, 8192 * sizeof(float), stream);
  nn3_kernel<<<dim3(128, 16), 256, 0, stream>>>(xyz1, xyz2, idxb, wgtb);
  transpose_cl<<<dim3(16, 4, 16), 256, 0, stream>>>(points2, p2t, 1024, 256);
  transpose_cl<<<dim3(64, 4, 16), 256, 0, stream>>>(points1, A1, 4096, 512);
  cvt_kernel<<<512, 256, 0, stream>>>(w0, w0b, 131072);
  cvt_kernel<<<256, 256, 0, stream>>>(w1, w1b, 65536);
  interp_kernel<<<1024, 256, 0, stream>>>(p2t, idxb, wgtb, A1);
  gemm_kernel<0><<<dim3(512, 2), 256, 0, stream>>>(A1, w0b, b0, Y, 512, sums0, sumsq0, nullptr, nullptr);
  bnprep_kernel<<<1, 256, 0, stream>>>(sums0, sumsq0, g0, be0, scale0, shift0);
  gemm_kernel<1><<<dim3(512, 2), 256, 0, stream>>>(Y, w1b, b1, Y2, 256, sums1, sumsq1, scale0, shift0);
  bnprep_kernel<<<1, 256, 0, stream>>>(sums1, sumsq1, g1, be1, scale1, shift1);
  bnrelu_tr_kernel<<<dim3(64, 1, 16), 256, 0, stream>>>(Y2, scale1, shift1, out);
}

// Round 9
// 292.700 us; speedup vs baseline: 1.2499x; 1.0101x over previous
//
#include <hip/hip_runtime.h>
#include <stdint.h>

using u16 = unsigned short;
using short8 = __attribute__((ext_vector_type(8))) short;
using ushort8 = __attribute__((ext_vector_type(8))) unsigned short;
using f32x4  = __attribute__((ext_vector_type(4))) float;
using u32x4  = __attribute__((ext_vector_type(4))) unsigned int;

__device__ __forceinline__ float bf2f(u16 u) {
  return __builtin_bit_cast(float, ((unsigned)u) << 16);
}
__device__ __forceinline__ u16 f2bf(float f) {
  unsigned u = __builtin_bit_cast(unsigned, f);
  u += 0x7FFFu + ((u >> 16) & 1u);   // RNE
  return (u16)(u >> 16);
}
// BN+ReLU on a packed pair of bf16 (used by the fused gemm2 staging path)
__device__ __forceinline__ unsigned bn2(unsigned w, float a0, float s0, float a1, float s1) {
  float f0 = bf2f((u16)(w & 0xFFFFu)) * a0 + s0;
  float f1 = bf2f((u16)(w >> 16))     * a1 + s1;
  f0 = f0 > 0.0f ? f0 : 0.0f;
  f1 = f1 > 0.0f ? f1 : 0.0f;
  return (unsigned)f2bf(f0) | ((unsigned)f2bf(f1) << 16);
}

// branchless insert of (d,s) into sorted top-3; strict < keeps earlier entries on ties
__device__ __forceinline__ void ins3(float& d0, float& d1, float& d2,
                                     int& i0, int& i1, int& i2, float d, int s) {
  bool c0 = d < d0, c1 = d < d1, c2 = d < d2;
  d2 = c1 ? d1 : (c2 ? d : d2);
  i2 = c1 ? i1 : (c2 ? s : i2);
  d1 = c0 ? d0 : (c1 ? d : d1);
  i1 = c0 ? i0 : (c1 ? s : i1);
  d0 = c0 ? d : d0;
  i0 = c0 ? s : i0;
}

// ---------------- 3-NN + inverse-distance weights (fp32 in) ----------------
// grid (N/32, B), block 256. 8 threads per query, each scans 128 candidates;
// partial top-3s merged via shfl_xor (lanes 8q..8q+7 are in the same wave).
// LDS: 8 staggered regions of 128 candidates; region stride 516 floats
// (2064 B, 16B-aligned, bank shift of 4 per region) -> conflict-free b128 reads.
// Scan metric is d' = |c|^2 - 2*p.c (per-query constant r1 folded out).
__global__ __launch_bounds__(256, 8) void nn3_kernel(
    const float* __restrict__ xyz1, const float* __restrict__ xyz2,
    int* __restrict__ idx_out, float* __restrict__ w_out) {
  __shared__ __align__(16) float cand[8 * 516];  // 16512 B
  const int b = blockIdx.y;
  const int t = threadIdx.x;
  const float* x2 = xyz2 + b * 3072;
  for (int i = t; i < 1024; i += 256) {
    float x = x2[i], y = x2[1024 + i], z = x2[2048 + i];
    f32x4 v = { -2.0f * x, -2.0f * y, -2.0f * z, x*x + y*y + z*z };
    *(f32x4*)&cand[(i >> 7) * 516 + (i & 127) * 4] = v;
  }
  __syncthreads();
  const int q = t >> 3, sub = t & 7;
  const int n = blockIdx.x * 32 + q;
  const float* x1 = xyz1 + b * 12288;
  const float px = x1[n], py = x1[4096 + n], pz = x1[8192 + n];
  float d0 = 1e30f, d1 = 1e30f, d2 = 1e30f;
  int i0 = 0, i1 = 0, i2 = 0;
  const int sbeg = sub << 7;
  const float* reg = &cand[sub * 516];
  #pragma unroll 4
  for (int ii = 0; ii < 128; ++ii) {
    f32x4 c = *(const f32x4*)(reg + ii * 4);
    float d = __builtin_fmaf(px, c[0],
              __builtin_fmaf(py, c[1],
              __builtin_fmaf(pz, c[2], c[3])));
    ins3(d0, d1, d2, i0, i1, i2, d, sbeg + ii);
  }
  // merge 8 partial lists, butterfly; a-list is always the lower-index range
  // on sub==0's tree -> ties keep earlier scan index.
  for (int st = 1; st <= 4; st <<= 1) {
    float e0 = __shfl_xor(d0, st), e1 = __shfl_xor(d1, st), e2 = __shfl_xor(d2, st);
    int   j0 = __shfl_xor(i0, st), j1 = __shfl_xor(i1, st), j2 = __shfl_xor(i2, st);
    ins3(d0, d1, d2, i0, i1, i2, e0, j0);
    ins3(d0, d1, d2, i0, i1, i2, e1, j1);
    ins3(d0, d1, d2, i0, i1, i2, e2, j2);
  }
  if (sub == 0) {
    const float r1 = px*px + py*py + pz*pz;  // add the folded-out constant back
    float w0 = 1.0f/(d0 + r1 + 1e-8f), w1 = 1.0f/(d1 + r1 + 1e-8f), w2 = 1.0f/(d2 + r1 + 1e-8f);
    float inv = 1.0f/(w0 + w1 + w2);
    const int pos = b * 4096 + n;
    idx_out[pos*3+0] = i0; idx_out[pos*3+1] = i1; idx_out[pos*3+2] = i2;
    w_out[pos*3+0] = w0*inv; w_out[pos*3+1] = w1*inv; w_out[pos*3+2] = w2*inv;
  }
}

// ---------------- [C=256][L] fp32 -> [L][C] bf16 transpose ----------------
// grid (L/64, 256/64, B), block 256. Write side: ushort2/lane (256 B/wave).
__global__ __launch_bounds__(256) void transpose_cl(
    const float* __restrict__ in, u16* __restrict__ out, int L, int rstride) {
  __shared__ u16 tile[64][66];
  const int b = blockIdx.z;
  in  += (size_t)b * 256 * L;
  out += (size_t)b * L * rstride;
  const int n0 = blockIdx.x * 64, c0 = blockIdx.y * 64;
  const int t = threadIdx.x, ln = t & 63, grp = t >> 6;
  for (int p = 0; p < 16; ++p) {
    int cc = p*4 + grp;
    tile[cc][ln] = f2bf(in[(size_t)(c0 + cc) * L + n0 + ln]);
  }
  __syncthreads();
  const int ln2 = t & 31, grp2 = t >> 5;      // 32 channel-pairs x 8 n-rows/iter
  for (int p = 0; p < 8; ++p) {
    int nn = p*8 + grp2;
    ushort2 v;
    v.x = tile[ln2*2][nn];
    v.y = tile[ln2*2 + 1][nn];
    *(ushort2*)&out[(size_t)(n0 + nn) * rstride + c0 + ln2*2] = v;
  }
}

// ---------------- fp32 -> bf16 weight conversion ----------------
__global__ __launch_bounds__(256) void cvt_kernel(const float* __restrict__ in,
                                                  u16* __restrict__ out, int n) {
  int i = blockIdx.x * 256 + threadIdx.x;
  if (i < n) out[i] = f2bf(in[i]);
}

// ---------------- 3-NN feature interpolation into A1 cols 256..511 ----------------
// grid 1024, block 256: 8 lane-groups of 32, each group does one position with
// ushort8 (16B) gathers; 8 iterations -> 64 positions per block.
__global__ __launch_bounds__(256) void interp_kernel(
    const u16* __restrict__ p2t, const int* __restrict__ idx,
    const float* __restrict__ wgt, u16* __restrict__ A1) {
  const int t = threadIdx.x;
  const int ln = t & 31, grp = t >> 5;
  const int c0 = ln * 8;
  for (int i = 0; i < 8; ++i) {
    const int pos = blockIdx.x * 64 + i * 8 + grp;
    const int b = pos >> 12;
    const int j0 = idx[pos*3+0], j1 = idx[pos*3+1], j2 = idx[pos*3+2];
    const float w0 = wgt[pos*3+0], w1 = wgt[pos*3+1], w2 = wgt[pos*3+2];
    ushort8 v0 = *(const ushort8*)(p2t + ((size_t)(b*1024 + j0)) * 256 + c0);
    ushort8 v1 = *(const ushort8*)(p2t + ((size_t)(b*1024 + j1)) * 256 + c0);
    ushort8 v2 = *(const ushort8*)(p2t + ((size_t)(b*1024 + j2)) * 256 + c0);
    ushort8 o;
    #pragma unroll
    for (int j = 0; j < 8; ++j)
      o[j] = f2bf(w0*bf2f(v0[j]) + w1*bf2f(v1[j]) + w2*bf2f(v2[j]));
    *(ushort8*)(A1 + (size_t)pos*512 + 256 + c0) = o;
  }
}

// ---------------- bf16 GEMM + fused per-channel stats (+optional fused BN) ----
// Y[m][n] = sum_k Ain[m][k]*Bw[n][k] + bias[n], where Ain = A (FUSE=0) or
// Ain = relu(A*bn_scale[k]+bn_shift[k]) applied during staging (FUSE=1, bit-
// identical to the old standalone bnrelu kernel's bf16 output).
// grid (M/128, N/128), block 256 (4 waves, 2x2 of 64x64 per wave).
// K-loop: round-1 compiler-scheduled structure (reg-staged, 2 barriers/step;
// manual pipelines all regressed r3-r5), BK=64 (r8: 46->41 us).
// LDS row stride 72 u16 = 144 B: uniform 8 lanes/16B window on both sides.
// Stats: wave shfl-reduce -> LDS atomic (dead As reuse) -> one global atomic
// per col per block into 8-way banked sums[8][256] (r6/r7 contention lesson).
template <int FUSE>
__global__ __launch_bounds__(256) void gemm_kernel(
    const u16* __restrict__ A, const u16* __restrict__ Bw,
    const float* __restrict__ bias, u16* __restrict__ Y, int K,
    float* __restrict__ sums, float* __restrict__ sumsq,
    const float* __restrict__ bn_scale, const float* __restrict__ bn_shift) {
  __shared__ __align__(16) u16 As[128*72];
  __shared__ __align__(16) u16 Bs[128*72];
  const int t = threadIdx.x;
  const int m0 = blockIdx.x * 128, n0 = blockIdx.y * 128;
  const int wave = t >> 6, l = t & 63;
  const int wm = wave & 1, wn = wave >> 1;
  const int lc = l & 15, quad = l >> 4;
  f32x4 acc[4][4] = {};
  const int r = t >> 3, kc = (t & 7) * 8;   // staging: 8 threads/row, 16B each
  for (int k0 = 0; k0 < K; k0 += 64) {
    f32x4 sc_lo, sc_hi, sh_lo, sh_hi;
    if (FUSE) {
      sc_lo = *(const f32x4*)&bn_scale[k0 + kc];
      sc_hi = *(const f32x4*)&bn_scale[k0 + kc + 4];
      sh_lo = *(const f32x4*)&bn_shift[k0 + kc];
      sh_hi = *(const f32x4*)&bn_shift[k0 + kc + 4];
    }
    #pragma unroll
    for (int p = 0; p < 4; ++p) {
      const int row = p*32 + r;
      u32x4 va = *(const u32x4*)&A [(size_t)(m0 + row)*K + k0 + kc];
      u32x4 vb = *(const u32x4*)&Bw[(size_t)(n0 + row)*K + k0 + kc];
      if (FUSE) {
        va[0] = bn2(va[0], sc_lo[0], sh_lo[0], sc_lo[1], sh_lo[1]);
        va[1] = bn2(va[1], sc_lo[2], sh_lo[2], sc_lo[3], sh_lo[3]);
        va[2] = bn2(va[2], sc_hi[0], sh_hi[0], sc_hi[1], sh_hi[1]);
        va[3] = bn2(va[3], sc_hi[2], sh_hi[2], sc_hi[3], sh_hi[3]);
      }
      *(u32x4*)&As[row*72 + kc] = va;
      *(u32x4*)&Bs[row*72 + kc] = vb;
    }
    __syncthreads();
    #pragma unroll
    for (int h = 0; h < 2; ++h) {
      short8 af[4], bfv[4];
      for (int tm = 0; tm < 4; ++tm)
        af[tm] = *(const short8*)&As[(wm*64 + tm*16 + lc)*72 + h*32 + quad*8];
      for (int tn = 0; tn < 4; ++tn)
        bfv[tn] = *(const short8*)&Bs[(wn*64 + tn*16 + lc)*72 + h*32 + quad*8];
      for (int tm = 0; tm < 4; ++tm)
        for (int tn = 0; tn < 4; ++tn)
          acc[tm][tn] = __builtin_amdgcn_mfma_f32_16x16x32_bf16(af[tm], bfv[tn], acc[tm][tn], 0, 0, 0);
    }
    __syncthreads();
  }
  // As is dead now -> reuse 1 KiB as the block's stats scratch.
  float* sl = (float*)As;            // sl[0..127]=sum per block-col, sl[128..255]=sumsq
  if (t < 256) sl[t] = 0.0f;
  __syncthreads();
  for (int tn = 0; tn < 4; ++tn) {
    const int colL = wn*64 + tn*16 + lc;          // col within block [0,128)
    const float bb = bias[n0 + colL];
    float s = 0.0f, q = 0.0f;
    for (int tm = 0; tm < 4; ++tm) {
      const int row = m0 + wm*64 + tm*16 + quad*4;
      for (int rr = 0; rr < 4; ++rr) {
        float v = acc[tm][tn][rr] + bb;           // C/D: col=lane&15, row=quad*4+reg
        Y[(size_t)(row + rr)*256 + n0 + colL] = f2bf(v);
        s += v; q += v*v;
      }
    }
    // reduce the 4 quads holding this col, then LDS-atomic (2 waves/addr)
    s += __shfl_xor(s, 16); s += __shfl_xor(s, 32);
    q += __shfl_xor(q, 16); q += __shfl_xor(q, 32);
    if (quad == 0) {
      atomicAdd(&sl[colL], s);
      atomicAdd(&sl[128 + colL], q);
    }
  }
  __syncthreads();
  if (t < 128) {                     // one global atomic per col per block, 8-banked
    const int bank = (blockIdx.x & 7) * 256;
    atomicAdd(&sums [bank + n0 + t], sl[t]);
    atomicAdd(&sumsq[bank + n0 + t], sl[128 + t]);
  }
}

// sums/sumsq are [8][256] banks; reduce banks here.
__global__ void bnprep_kernel(const float* __restrict__ sums, const float* __restrict__ sumsq,
                              const float* __restrict__ g, const float* __restrict__ be,
                              float* __restrict__ scale, float* __restrict__ shift) {
  const int t = threadIdx.x;
  float s = 0.0f, q = 0.0f;
  for (int k = 0; k < 8; ++k) { s += sums[k*256 + t]; q += sumsq[k*256 + t]; }
  const float inv_n = 1.0f / 65536.0f;
  float mean = s * inv_n;
  float var = q * inv_n - mean*mean;  // biased var, matches jnp.var
  float a = g[t] * rsqrtf(var + 1e-5f);
  scale[t] = a;
  shift[t] = be[t] - mean * a;
}

// ---------------- BN+ReLU + transpose to [b][c][n] fp32 output ----------------
// grid (64, 1, 16), block 256. Vectorized: ushort4 channel-quad reads (16
// instead of 64 global loads), ds_write_b64 into [n][c] tile (stride 266:
// 133*ln mod 32 coprime -> conflict-free u32 reads in phase 2).
__global__ __launch_bounds__(256) void bnrelu_tr_kernel(
    const u16* __restrict__ Y, const float* __restrict__ scale,
    const float* __restrict__ shift, float* __restrict__ out) {
  __shared__ u16 tile[64][266];   // [n - n0][channel]
  const int t = threadIdx.x;
  const int b = blockIdx.z;
  const int n0 = blockIdx.x * 64;
  const int ln = t & 63, grp = t >> 6;
  const int c0 = ln * 4;
  const f32x4 a4 = *(const f32x4*)&scale[c0];
  const f32x4 s4 = *(const f32x4*)&shift[c0];
  for (int it = 0; it < 16; ++it) {
    const int nn = it*4 + grp;
    size_t pos = (size_t)b*4096 + n0 + nn;
    ushort4 v = *(const ushort4*)&Y[pos*256 + c0];
    ushort4 o;
    float f0 = bf2f(v.x)*a4[0] + s4[0];
    float f1 = bf2f(v.y)*a4[1] + s4[1];
    float f2v = bf2f(v.z)*a4[2] + s4[2];
    float f3 = bf2f(v.w)*a4[3] + s4[3];
    o.x = f2bf(f0 > 0.0f ? f0 : 0.0f);
    o.y = f2bf(f1 > 0.0f ? f1 : 0.0f);
    o.z = f2bf(f2v > 0.0f ? f2v : 0.0f);
    o.w = f2bf(f3 > 0.0f ? f3 : 0.0f);
    *(ushort4*)&tile[nn][c0] = o;   // ds_write_b64
  }
  __syncthreads();
  // phase 2: lane = n index; each iteration covers 2 channels via one u32 read
  for (int p = 0; p < 32; ++p) {
    const int oo = p*8 + grp*2;
    ushort2 v = *(const ushort2*)&tile[ln][oo];   // u32 LDS read, conflict-free
    out[((size_t)b*256 + oo    )*4096 + n0 + ln] = bf2f(v.x);
    out[((size_t)b*256 + oo + 1)*4096 + n0 + ln] = bf2f(v.y);
  }
}

extern "C" void kernel_launch(void* const* d_in, const int* in_sizes, int n_in,
                              void* d_out, int out_size, void* d_ws, size_t ws_size,
                              hipStream_t stream) {
  const float* xyz1    = (const float*)d_in[0];
  const float* xyz2    = (const float*)d_in[1];
  const float* points1 = (const float*)d_in[2];
  const float* points2 = (const float*)d_in[3];
  const float* w0      = (const float*)d_in[4];
  const float* b0      = (const float*)d_in[5];
  const float* g0      = (const float*)d_in[6];
  const float* be0     = (const float*)d_in[7];
  const float* w1      = (const float*)d_in[8];
  const float* b1      = (const float*)d_in[9];
  const float* g1      = (const float*)d_in[10];
  const float* be1     = (const float*)d_in[11];
  float* out = (float*)d_out;

  // ---- workspace layout (~107 MiB used) ----
  char* ws = (char*)d_ws;
  u16*   A1   = (u16*)ws;                          // [65536][512] bf16, 64 MiB (dead after gemm1)
  u16*   Y2   = (u16*)ws;                          // [65536][256] bf16, 32 MiB (overlays dead A1)
  u16*   Y    = (u16*)(ws + (64ull  << 20));       // [65536][256] bf16, 32 MiB
  u16*   p2t  = (u16*)(ws + (96ull  << 20));       // [16*1024][256] bf16, 8 MiB
  int*   idxb = (int*)(ws + (104ull << 20));       // 768 KiB
  float* wgtb = (float*)(ws + (105ull << 20));     // 768 KiB
  u16*   w0b  = (u16*)(ws + (106ull << 20));       // [256][512] bf16, 256 KiB
  u16*   w1b  = (u16*)(ws + (106ull << 20) + (256u << 10)); // [256][256] bf16, 128 KiB
  float* stats= (float*)(ws + (106ull << 20) + (512u << 10)); // 9216 floats

  // banked accumulators [8][256] each, then scale/shift
  float* sums0  = stats;          // 2048
  float* sumsq0 = stats + 2048;   // 2048
  float* sums1  = stats + 4096;   // 2048
  float* sumsq1 = stats + 6144;   // 2048
  float* scale0 = stats + 8192, *shift0 = stats + 8448;
  float* scale1 = stats + 8704, *shift1 = stats + 8960;

  hipMemsetAsync(stats, 0, 8192 * sizeof(float), stream);
  nn3_kernel<<<dim3(128, 16), 256, 0, stream>>>(xyz1, xyz2, idxb, wgtb);
  transpose_cl<<<dim3(16, 4, 16), 256, 0, stream>>>(points2, p2t, 1024, 256);
  transpose_cl<<<dim3(64, 4, 16), 256, 0, stream>>>(points1, A1, 4096, 512);
  cvt_kernel<<<512, 256, 0, stream>>>(w0, w0b, 131072);
  cvt_kernel<<<256, 256, 0, stream>>>(w1, w1b, 65536);
  interp_kernel<<<1024, 256, 0, stream>>>(p2t, idxb, wgtb, A1);
  gemm_kernel<0><<<dim3(512, 2), 256, 0, stream>>>(A1, w0b, b0, Y, 512, sums0, sumsq0, nullptr, nullptr);
  bnprep_kernel<<<1, 256, 0, stream>>>(sums0, sumsq0, g0, be0, scale0, shift0);
  gemm_kernel<1><<<dim3(512, 2), 256, 0, stream>>>(Y, w1b, b1, Y2, 256, sums1, sumsq1, scale0, shift0);
  bnprep_kernel<<<1, 256, 0, stream>>>(sums1, sumsq1, g1, be1, scale1, shift1);
  bnrelu_tr_kernel<<<dim3(64, 1, 16), 256, 0, stream>>>(Y2, scale1, shift1, out);
}